// Round 6
// baseline (787.446 us; speedup 1.0000x reference)
//
#include <hip/hip_runtime.h>

// Pin2PinAttraction: sum_i w[i] * ((x[a_i]-x[b_i])^2 + (y[a_i]-y[b_i])^2)
//
// r6: fix both r5 phases.
//  - scatter: block-local counting sort (regs -> LDS-sorted -> coalesced
//    copy-out) kills the 2x write amplification seen in r5 (WRITE 197MB).
//  - gather: 16x16=256 bins (1MB slices); per-XCD work queues keyed by the
//    PHYSICAL XCC_ID (s_getreg), ordered (j, row-pair) so working set is
//    2MB row slices + 1MB col slice < 4MB L2; blocks steal from other
//    queues when empty => correct under any WG->XCD mapping.

typedef int   i32x4 __attribute__((ext_vector_type(4)));
typedef int   i32x2 __attribute__((ext_vector_type(2)));
typedef float f32x2 __attribute__((ext_vector_type(2)));

#define NSLICE 16
#define NBINS  256            // NSLICE * NSLICE
#define CHUNK  4096
#define EPT    16             // CHUNK / 256
#define SUBS   16             // sub-chunks per bin (queue granularity)
#define QITEMS (32 * SUBS)    // items per XCD queue: 2 rows * 16 cols * SUBS

__device__ __forceinline__ int xcc_id() {
    // HW_REG_XCC_ID = id 20, offset 0, size 4 (gfx940+). If the id were
    // wrong we'd get a bogus-but-constant value; stealing keeps it correct.
    return __builtin_amdgcn_s_getreg(20 | (0 << 6) | ((4 - 1) << 11)) & 7;
}

// ---------------------------------------------------------------- pack
__global__ __launch_bounds__(256) void pack_xy_kernel(
    const float* __restrict__ pin_pos,
    f32x2*       __restrict__ xy,
    int num_pins)
{
    const int tid    = blockIdx.x * blockDim.x + threadIdx.x;
    const int stride = gridDim.x * blockDim.x;
    const float* __restrict__ xs = pin_pos;
    const float* __restrict__ ys = pin_pos + num_pins;
    for (int i = tid; i < num_pins; i += stride) {
        f32x2 v; v.x = xs[i]; v.y = ys[i];
        xy[i] = v;
    }
}

// ---------------------------------------------------------------- scatter (counting sort per chunk)
__global__ __launch_bounds__(256) void scatter_sort_kernel(
    const int*   __restrict__ pairs,    // [2*num_pairs] interleaved
    const float* __restrict__ weights,  // [num_pairs]
    const f32x2* __restrict__ xy,       // packed table (overflow path)
    i32x2*       __restrict__ ab_out,   // [NBINS*cap]
    float*       __restrict__ w_out,    // [NBINS*cap]
    int*         __restrict__ cursors,  // [NBINS], zeroed
    float*       __restrict__ out,
    int num_pairs, int shift, int cap)
{
    const int tid = threadIdx.x;
    const i32x2* __restrict__ pr = (const i32x2*)pairs;

    __shared__ i32x2 sab[CHUNK];      // 32 KB  (sorted staging)
    __shared__ float swt[CHUNK];      // 16 KB
    __shared__ int hist[NBINS];
    __shared__ int sc[NBINS];
    __shared__ int lbase[NBINS];
    __shared__ int gbase[NBINS];

    const int nchunks = (num_pairs + CHUNK - 1) / CHUNK;
    float facc = 0.0f;                // overflow fallback (normally 0)

    for (int c = blockIdx.x; c < nchunks; c += gridDim.x) {
        const int i0 = c * CHUNK;
        const int n  = min(CHUNK, num_pairs - i0);

        hist[tid] = 0;                // blockDim == NBINS == 256
        __syncthreads();

        // A: load 16 pairs/thread into registers (static idx), histogram
        int   pa_[EPT], pb_[EPT];
        float pw_[EPT];
#pragma unroll
        for (int u = 0; u < EPT; ++u) {
            const int e = u * 256 + tid;
            if (e < n) {
                i32x2 p = __builtin_nontemporal_load(pr + i0 + e);
                float w = __builtin_nontemporal_load(weights + i0 + e);
                pa_[u] = p.x; pb_[u] = p.y; pw_[u] = w;
                int bin = ((p.x >> shift) << 4) | (p.y >> shift);
                atomicAdd(&hist[bin], 1);
            }
        }
        __syncthreads();

        // exclusive scan of hist (Hillis-Steele over 256)
        sc[tid] = hist[tid];
        __syncthreads();
        for (int d = 1; d < NBINS; d <<= 1) {
            int v = (tid >= d) ? sc[tid - d] : 0;
            __syncthreads();
            sc[tid] += v;
            __syncthreads();
        }
        lbase[tid] = sc[tid] - hist[tid];
        gbase[tid] = atomicAdd(&cursors[tid], hist[tid]);
        hist[tid]  = 0;               // reuse as rank counters
        __syncthreads();

        // B: scatter into bin-sorted LDS staging
#pragma unroll
        for (int u = 0; u < EPT; ++u) {
            const int e = u * 256 + tid;
            if (e < n) {
                int bin = ((pa_[u] >> shift) << 4) | (pb_[u] >> shift);
                int r   = atomicAdd(&hist[bin], 1);
                int d   = lbase[bin] + r;
                i32x2 p; p.x = pa_[u]; p.y = pb_[u];
                sab[d] = p; swt[d] = pw_[u];
            }
        }
        __syncthreads();

        // C: linear LDS walk -> per-bin contiguous global runs (coalesced)
        for (int e = tid; e < n; e += 256) {
            i32x2 p = sab[e];
            float w = swt[e];
            int bin = ((p.x >> shift) << 4) | (p.y >> shift);
            long pos = (long)gbase[bin] + (e - lbase[bin]);
            if (pos < cap) {
                ab_out[(long)bin * cap + pos] = p;
                w_out [(long)bin * cap + pos] = w;
            } else {
                f32x2 A = xy[p.x], B = xy[p.y];
                float dx = A.x - B.x, dy = A.y - B.y;
                facc += w * (dx * dx + dy * dy);
            }
        }
        __syncthreads();              // staging reused next chunk
    }

    // reduce (normally zero) overflow contributions
    for (int off = 32; off > 0; off >>= 1)
        facc += __shfl_down(facc, off, 64);
    __shared__ float wave_sums[4];
    const int lane = tid & 63, wid = tid >> 6;
    if (lane == 0) wave_sums[wid] = facc;
    __syncthreads();
    if (tid == 0) {
        float s = wave_sums[0] + wave_sums[1] + wave_sums[2] + wave_sums[3];
        if (s != 0.0f) atomicAdd(out, s);
    }
}

// ---------------------------------------------------------------- gather (per-XCD queues + stealing)
__global__ __launch_bounds__(256) void gather_binned_kernel(
    const f32x2* __restrict__ xy,
    const i32x2* __restrict__ ab,
    const float* __restrict__ wbin,
    const int*   __restrict__ cursors,
    int*         __restrict__ qcur,    // [8], zeroed
    float*       __restrict__ out,
    int cap)
{
    const int tid = threadIdx.x;
    const int myk = xcc_id();
    float acc = 0.0f;

    __shared__ int item_s;

    for (int probe = 0; probe < 8; ++probe) {
        const int q = (myk + probe) & 7;    // own queue first, then steal
        for (;;) {
            if (tid == 0) item_s = atomicAdd(&qcur[q], 1);
            __syncthreads();
            const int t = item_s;
            __syncthreads();                // all read before next write
            if (t >= QITEMS) break;

            // item order: col slice j outer, row-pair inner =>
            // working set = 2 row slices (resident) + current col slice
            const int s   = t / SUBS;       // 0..31
            const int sub = t % SUBS;
            const int j   = s >> 1;
            const int row = 2 * q + (s & 1);
            const int bin = row * NSLICE + j;

            int cnt = cursors[bin];
            if (cnt > cap) cnt = cap;
            const int k0 = (int)((long)cnt * sub       / SUBS);
            const int k1 = (int)((long)cnt * (sub + 1) / SUBS);
            const i32x2* __restrict__ abp = ab   + (long)bin * cap;
            const float* __restrict__ wp  = wbin + (long)bin * cap;
            for (int k = k0 + tid; k < k1; k += 256) {
                i32x2 p = __builtin_nontemporal_load(abp + k);
                float w = __builtin_nontemporal_load(wp + k);
                f32x2 A = xy[p.x], B = xy[p.y];
                float dx = A.x - B.x, dy = A.y - B.y;
                acc += w * (dx * dx + dy * dy);
            }
        }
    }

    for (int off = 32; off > 0; off >>= 1)
        acc += __shfl_down(acc, off, 64);
    __shared__ float wave_sums[4];
    const int lane = tid & 63, wid = tid >> 6;
    if (lane == 0) wave_sums[wid] = acc;
    __syncthreads();
    if (tid == 0) {
        float s = wave_sums[0] + wave_sums[1] + wave_sums[2] + wave_sums[3];
        atomicAdd(out, s);
    }
}

// ---------------------------------------------------------------- r3 fallback
__global__ __launch_bounds__(256) void p2p_gather_kernel(
    const f32x2* __restrict__ xy,
    const float* __restrict__ weights,
    const int*   __restrict__ pairs,
    float*       __restrict__ out,
    int num_pairs)
{
    const int tid    = blockIdx.x * blockDim.x + threadIdx.x;
    const int stride = gridDim.x * blockDim.x;
    float acc = 0.0f;
    const i32x4* __restrict__ pairs4 = (const i32x4*)pairs;
    const f32x2* __restrict__ w2     = (const f32x2*)weights;
    const int n2 = num_pairs >> 1;
    for (int i = tid; i < n2; i += stride) {
        i32x4 p = __builtin_nontemporal_load(pairs4 + i);
        f32x2 w = __builtin_nontemporal_load(w2 + i);
        f32x2 A0 = xy[p.x], B0 = xy[p.y];
        f32x2 A1 = xy[p.z], B1 = xy[p.w];
        float dx0 = A0.x - B0.x, dy0 = A0.y - B0.y;
        float dx1 = A1.x - B1.x, dy1 = A1.y - B1.y;
        acc += w.x * (dx0 * dx0 + dy0 * dy0);
        acc += w.y * (dx1 * dx1 + dy1 * dy1);
    }
    if ((num_pairs & 1) && tid == 0) {
        int a = pairs[2 * (num_pairs - 1)];
        int b = pairs[2 * (num_pairs - 1) + 1];
        f32x2 A = xy[a], B = xy[b];
        float dx = A.x - B.x, dy = A.y - B.y;
        acc += weights[num_pairs - 1] * (dx * dx + dy * dy);
    }
    for (int off = 32; off > 0; off >>= 1)
        acc += __shfl_down(acc, off, 64);
    __shared__ float wave_sums[4];
    const int lane = threadIdx.x & 63, wid = threadIdx.x >> 6;
    if (lane == 0) wave_sums[wid] = acc;
    __syncthreads();
    if (threadIdx.x == 0) {
        float s = wave_sums[0] + wave_sums[1] + wave_sums[2] + wave_sums[3];
        atomicAdd(out, s);
    }
}

// ---------------------------------------------------------------- direct (no-ws)
__global__ __launch_bounds__(256) void p2p_direct_kernel(
    const float* __restrict__ pin_pos,
    const float* __restrict__ weights,
    const int*   __restrict__ pairs,
    float*       __restrict__ out,
    int num_pins, int num_pairs)
{
    const float* __restrict__ xs = pin_pos;
    const float* __restrict__ ys = pin_pos + num_pins;
    const int tid    = blockIdx.x * blockDim.x + threadIdx.x;
    const int stride = gridDim.x * blockDim.x;
    float acc = 0.0f;
    for (int i = tid; i < num_pairs; i += stride) {
        int a = pairs[2 * i], b = pairs[2 * i + 1];
        float dx = xs[a] - xs[b], dy = ys[a] - ys[b];
        acc += weights[i] * (dx * dx + dy * dy);
    }
    for (int off = 32; off > 0; off >>= 1)
        acc += __shfl_down(acc, off, 64);
    __shared__ float wave_sums[4];
    const int lane = threadIdx.x & 63, wid = threadIdx.x >> 6;
    if (lane == 0) wave_sums[wid] = acc;
    __syncthreads();
    if (threadIdx.x == 0) {
        float s = wave_sums[0] + wave_sums[1] + wave_sums[2] + wave_sums[3];
        atomicAdd(out, s);
    }
}

// ---------------------------------------------------------------- launch
extern "C" void kernel_launch(void* const* d_in, const int* in_sizes, int n_in,
                              void* d_out, int out_size, void* d_ws, size_t ws_size,
                              hipStream_t stream) {
    const float* pin_pos = (const float*)d_in[0];
    const float* weights = (const float*)d_in[1];
    const int*   pairs   = (const int*)d_in[2];

    const int num_pins  = in_sizes[0] / 2;
    const int num_pairs = in_sizes[1];

    float* out = (float*)d_out;
    hipMemsetAsync(out, 0, sizeof(float), stream);  // d_out poisoned each call

    const int block = 256;

    // 16 slices: (num_pins-1)>>shift must be <= 15
    int shift = 0;
    while (((unsigned)(num_pins - 1) >> shift) > 15u) ++shift;

    // ws layout: [xy 8B*num_pins][cursors 256*4 + qcur 8*4][ab 8B*NBINS*cap][w 4B*NBINS*cap]
    const size_t xy_bytes = (size_t)num_pins * sizeof(f32x2);
    const size_t cur_off  = (xy_bytes + 255) & ~(size_t)255;
    const size_t ab_off   = (cur_off + (NBINS + 8) * sizeof(int) + 255) & ~(size_t)255;

    long cap = 0;
    if (ws_size > ab_off) cap = (long)((ws_size - ab_off) / (NBINS * 12));
    if (cap > 60000) cap = 60000;

    // expected max bin ~34.4k (uneven last slice at shift=17); overflow path
    // keeps correctness anyway.
    if (cap >= 36000) {
        f32x2* xy      = (f32x2*)d_ws;
        int*   cursors = (int*)((char*)d_ws + cur_off);
        int*   qcur    = cursors + NBINS;
        i32x2* ab      = (i32x2*)((char*)d_ws + ab_off);
        float* wbin    = (float*)((char*)d_ws + ab_off + (size_t)NBINS * cap * sizeof(i32x2));

        hipMemsetAsync(cursors, 0, (NBINS + 8) * sizeof(int), stream);
        pack_xy_kernel<<<2048, block, 0, stream>>>(pin_pos, xy, num_pins);
        scatter_sort_kernel<<<1024, block, 0, stream>>>(
            pairs, weights, xy, ab, wbin, cursors, out,
            num_pairs, shift, (int)cap);
        gather_binned_kernel<<<2048, block, 0, stream>>>(
            xy, ab, wbin, cursors, qcur, out, (int)cap);
    } else if (ws_size >= xy_bytes) {
        f32x2* xy = (f32x2*)d_ws;
        pack_xy_kernel<<<2048, block, 0, stream>>>(pin_pos, xy, num_pins);
        p2p_gather_kernel<<<2048, block, 0, stream>>>(
            xy, weights, pairs, out, num_pairs);
    } else {
        p2p_direct_kernel<<<2048, block, 0, stream>>>(
            pin_pos, weights, pairs, out, num_pins, num_pairs);
    }
}

// Round 7
// 332.185 us; speedup vs baseline: 2.3705x; 2.3705x over previous
//
#include <hip/hip_runtime.h>

// Pin2PinAttraction: sum_i w[i] * ((x[a_i]-x[b_i])^2 + (y[a_i]-y[b_i])^2)
//
// r7: scatter/binning abandoned (r5: 172us + 2x write amp; r6: 395us + 10x
// write amp — multi-region scattered writes cost several x payload on this
// chip). Return to the proven r3 single-pass gather (217us) and raise MLP:
// 4 pairs per iteration = 8 independent 8B gathers in flight per wave
// (r3 had ~4; in-flight-bytes math says r3 was concurrency-limited at
// 3.7 TB/s, not fabric-limited).

typedef int   i32x4 __attribute__((ext_vector_type(4)));
typedef float f32x4 __attribute__((ext_vector_type(4)));
typedef float f32x2 __attribute__((ext_vector_type(2)));

// ---------------------------------------------------------------- pack
// Interleave x/y (two lines 8MB apart) into one float2 per pin [r3 win].
__global__ __launch_bounds__(256) void pack_xy_kernel(
    const float* __restrict__ pin_pos,
    f32x2*       __restrict__ xy,
    int num_pins)
{
    const int tid    = blockIdx.x * blockDim.x + threadIdx.x;
    const int stride = gridDim.x * blockDim.x;
    const float* __restrict__ xs = pin_pos;
    const float* __restrict__ ys = pin_pos + num_pins;
    for (int i = tid; i < num_pins; i += stride) {
        f32x2 v; v.x = xs[i]; v.y = ys[i];
        xy[i] = v;
    }
}

// ---------------------------------------------------------------- gather
__global__ __launch_bounds__(256) void p2p_gather_kernel(
    const f32x2* __restrict__ xy,      // [num_pins] packed {x,y}
    const float* __restrict__ weights, // [num_pairs]
    const int*   __restrict__ pairs,   // [2*num_pairs] interleaved
    float*       __restrict__ out,     // [1]
    int num_pairs)
{
    const int tid    = blockIdx.x * blockDim.x + threadIdx.x;
    const int stride = gridDim.x * blockDim.x;

    const i32x4* __restrict__ pairs4 = (const i32x4*)pairs;  // 2 pairs / vec
    const f32x4* __restrict__ w4     = (const f32x4*)weights;
    const int n4 = num_pairs >> 2;   // groups of 4 pairs

    float acc0 = 0.0f, acc1 = 0.0f;

    for (int i = tid; i < n4; i += stride) {
        // streamed read-once: non-temporal (don't evict xy from L2)
        i32x4 pA = __builtin_nontemporal_load(pairs4 + 2 * i);
        i32x4 pB = __builtin_nontemporal_load(pairs4 + 2 * i + 1);
        f32x4 w  = __builtin_nontemporal_load(w4 + i);

        // 8 independent gathers issued before any use (MLP)
        f32x2 A0 = xy[pA.x], B0 = xy[pA.y];
        f32x2 A1 = xy[pA.z], B1 = xy[pA.w];
        f32x2 A2 = xy[pB.x], B2 = xy[pB.y];
        f32x2 A3 = xy[pB.z], B3 = xy[pB.w];

        float dx0 = A0.x - B0.x, dy0 = A0.y - B0.y;
        float dx1 = A1.x - B1.x, dy1 = A1.y - B1.y;
        float dx2 = A2.x - B2.x, dy2 = A2.y - B2.y;
        float dx3 = A3.x - B3.x, dy3 = A3.y - B3.y;

        acc0 += w.x * (dx0 * dx0 + dy0 * dy0);
        acc1 += w.y * (dx1 * dx1 + dy1 * dy1);
        acc0 += w.z * (dx2 * dx2 + dy2 * dy2);
        acc1 += w.w * (dx3 * dx3 + dy3 * dy3);
    }

    float acc = acc0 + acc1;

    // tail: up to 3 leftover pairs, thread 0 of block 0
    if (blockIdx.x == 0 && threadIdx.x == 0) {
        for (int i = n4 * 4; i < num_pairs; ++i) {
            int a = pairs[2 * i], b = pairs[2 * i + 1];
            f32x2 A = xy[a], B = xy[b];
            float dx = A.x - B.x, dy = A.y - B.y;
            acc += weights[i] * (dx * dx + dy * dy);
        }
    }

    // wave-64 butterfly reduce
    for (int off = 32; off > 0; off >>= 1)
        acc += __shfl_down(acc, off, 64);

    __shared__ float wave_sums[4];  // 256 threads = 4 waves
    const int lane = threadIdx.x & 63;
    const int wid  = threadIdx.x >> 6;
    if (lane == 0) wave_sums[wid] = acc;
    __syncthreads();

    if (threadIdx.x == 0) {
        float s = wave_sums[0] + wave_sums[1] + wave_sums[2] + wave_sums[3];
        atomicAdd(out, s);
    }
}

// ---------------------------------------------------------------- direct (no-ws)
__global__ __launch_bounds__(256) void p2p_direct_kernel(
    const float* __restrict__ pin_pos,
    const float* __restrict__ weights,
    const int*   __restrict__ pairs,
    float*       __restrict__ out,
    int num_pins, int num_pairs)
{
    const float* __restrict__ xs = pin_pos;
    const float* __restrict__ ys = pin_pos + num_pins;
    const int tid    = blockIdx.x * blockDim.x + threadIdx.x;
    const int stride = gridDim.x * blockDim.x;
    float acc = 0.0f;
    for (int i = tid; i < num_pairs; i += stride) {
        int a = pairs[2 * i], b = pairs[2 * i + 1];
        float dx = xs[a] - xs[b], dy = ys[a] - ys[b];
        acc += weights[i] * (dx * dx + dy * dy);
    }
    for (int off = 32; off > 0; off >>= 1)
        acc += __shfl_down(acc, off, 64);
    __shared__ float wave_sums[4];
    const int lane = threadIdx.x & 63, wid = threadIdx.x >> 6;
    if (lane == 0) wave_sums[wid] = acc;
    __syncthreads();
    if (threadIdx.x == 0) {
        float s = wave_sums[0] + wave_sums[1] + wave_sums[2] + wave_sums[3];
        atomicAdd(out, s);
    }
}

// ---------------------------------------------------------------- launch
extern "C" void kernel_launch(void* const* d_in, const int* in_sizes, int n_in,
                              void* d_out, int out_size, void* d_ws, size_t ws_size,
                              hipStream_t stream) {
    const float* pin_pos = (const float*)d_in[0];
    const float* weights = (const float*)d_in[1];
    const int*   pairs   = (const int*)d_in[2];
    // d_in[3] = pin_mask (unused by reference)

    const int num_pins  = in_sizes[0] / 2;
    const int num_pairs = in_sizes[1];

    float* out = (float*)d_out;
    hipMemsetAsync(out, 0, sizeof(float), stream);  // d_out poisoned each call

    const int block = 256;
    const int grid  = 2048;  // 8192 waves = device wave capacity

    const size_t xy_bytes = (size_t)num_pins * sizeof(f32x2);
    if (ws_size >= xy_bytes) {
        f32x2* xy = (f32x2*)d_ws;
        pack_xy_kernel<<<grid, block, 0, stream>>>(pin_pos, xy, num_pins);
        p2p_gather_kernel<<<grid, block, 0, stream>>>(
            xy, weights, pairs, out, num_pairs);
    } else {
        p2p_direct_kernel<<<grid, block, 0, stream>>>(
            pin_pos, weights, pairs, out, num_pins, num_pairs);
    }
}